// Round 6
// baseline (313.623 us; speedup 1.0000x reference)
//
#include <hip/hip_runtime.h>
#include <cstdint>
#include <cstddef>

typedef __bf16 bfloat;
typedef __bf16 bf16x8 __attribute__((ext_vector_type(8)));
typedef __bf16 bf16x4 __attribute__((ext_vector_type(4)));
typedef float  f32x4  __attribute__((ext_vector_type(4)));

static constexpr int D  = 1024;
static constexpr int S  = 2048;
static constexpr int B  = 2;
static constexpr int H  = 16;
static constexpr int DH = 64;
static constexpr int M  = B * S;
static constexpr int WMAT_N = 1024 * 1024;

#define MFMA_BF16(a, b, c) __builtin_amdgcn_mfma_f32_16x16x32_bf16((a), (b), (c), 0, 0, 0)

__device__ __forceinline__ void gl_lds16(const void* g, void* l) {
  __builtin_amdgcn_global_load_lds(
      (const __attribute__((address_space(1))) void*)g,
      (__attribute__((address_space(3))) void*)l, 16, 0, 0);
}

// ---------------- abs-sum reduce in f64 ----------------
__global__ void absum_kernel(const float* __restrict__ w0, const float* __restrict__ w1,
                             const float* __restrict__ w2, const float* __restrict__ w3,
                             double* __restrict__ sums) {
  int z = blockIdx.y;
  const float* w = (z == 0) ? w0 : (z == 1) ? w1 : (z == 2) ? w2 : w3;
  const float4* w4 = (const float4*)w;
  double s = 0.0;
  for (int i = blockIdx.x * blockDim.x + threadIdx.x; i < (WMAT_N / 4);
       i += gridDim.x * blockDim.x) {
    float4 v = w4[i];
    s += (double)fabsf(v.x) + (double)fabsf(v.y) + (double)fabsf(v.z) + (double)fabsf(v.w);
  }
  for (int off = 1; off < 64; off <<= 1) s += __shfl_xor(s, off, 64);
  __shared__ double ps[4];
  if ((threadIdx.x & 63) == 0) ps[threadIdx.x >> 6] = s;
  __syncthreads();
  if (threadIdx.x == 0) atomicAdd(&sums[z], ps[0] + ps[1] + ps[2] + ps[3]);
}

// ---------------- ternarize -> bf16 ----------------
__global__ void tern_kernel(const float* __restrict__ w0, const float* __restrict__ w1,
                            const float* __restrict__ w2, const float* __restrict__ w3,
                            bfloat* __restrict__ o0, bfloat* __restrict__ o1,
                            bfloat* __restrict__ o2, bfloat* __restrict__ o3,
                            const double* __restrict__ sums) {
  int z = blockIdx.y;
  const float* w = (z == 0) ? w0 : (z == 1) ? w1 : (z == 2) ? w2 : w3;
  bfloat* o = (z == 0) ? o0 : (z == 1) ? o1 : (z == 2) ? o2 : o3;
  double thr = sums[z] * (1.0 / (double)WMAT_N);
  const float4* w4 = (const float4*)w;
  for (int i = blockIdx.x * blockDim.x + threadIdx.x; i < (WMAT_N / 4);
       i += gridDim.x * blockDim.x) {
    float4 v = w4[i];
    bf16x4 r;
    r[0] = (bfloat)(((double)fabsf(v.x) > thr) ? (v.x > 0.f ? 1.f : -1.f) : 0.f);
    r[1] = (bfloat)(((double)fabsf(v.y) > thr) ? (v.y > 0.f ? 1.f : -1.f) : 0.f);
    r[2] = (bfloat)(((double)fabsf(v.z) > thr) ? (v.z > 0.f ? 1.f : -1.f) : 0.f);
    r[3] = (bfloat)(((double)fabsf(v.w) > thr) ? (v.w > 0.f ? 1.f : -1.f) : 0.f);
    *(bf16x4*)&o[(size_t)i * 4] = r;
  }
}

// -------- fused q/k/v projection v2: fp32 x staged directly (splitcvt
// fused into fragment read), BK=64, full-XOR 16B swizzle (2-way reads).
// q: hi/lo 2-pass MFMA, epilogue x softmax-scale, hi/lo bf16 out.
// k: hi/lo 2-pass, hi/lo out.  v: hi-only 1-pass, writes V^T [B][D][S].
__global__ __launch_bounds__(256) void qkv_gemm(
    const float* __restrict__ xq, const float* __restrict__ xk,
    const float* __restrict__ xv, const bfloat* __restrict__ wqt,
    const bfloat* __restrict__ wkt, const bfloat* __restrict__ wvt,
    bfloat* __restrict__ qmh, bfloat* __restrict__ qml,
    bfloat* __restrict__ kmh, bfloat* __restrict__ kml,
    bfloat* __restrict__ vtr) {
  constexpr int K = D;
  constexpr int N = D;
  __shared__ __align__(16) float  Xs[128 * 64];   // 32 KB fp32 A-tile
  __shared__ __align__(16) bfloat Ws[128 * 64];   // 16 KB ternary W-tile

  const int z = blockIdx.z;
  const float* A = (z == 0) ? xq : (z == 1) ? xk : xv;
  const bfloat* Wm = (z == 0) ? wqt : (z == 1) ? wkt : wvt;
  bfloat* Oh = (z == 0) ? qmh : kmh;
  bfloat* Ol = (z == 0) ? qml : kml;
  const bool split = (z < 2);
  const float scale = (z == 0) ? 0.18033688f : 1.f;  // 1/sqrt(64)*log2e on q

  const int t = threadIdx.x;
  const int w = t >> 6, lane = t & 63;
  const int quad = lane >> 4, l16 = lane & 15;
  const int wm = w >> 1, wn = w & 1;
  const int m0 = blockIdx.y * 128, n0 = blockIdx.x * 128;

  f32x4 acc[4][4] = {};

  const int r4 = lane >> 4, cp16 = lane & 15;  // A staging: 4 rows x 16 chunks
  const int r8 = lane >> 3, cp8 = lane & 7;    // W staging: 8 rows x 8 chunks

  for (int kk = 0; kk < K; kk += 64) {
#pragma unroll
    for (int g = 0; g < 8; g++) {
      int row = w * 32 + g * 4 + r4;
      int cl = cp16 ^ (row & 15);
      gl_lds16(A + (size_t)(m0 + row) * K + kk + cl * 4, Xs + (w * 32 + g * 4) * 64);
    }
#pragma unroll
    for (int g = 0; g < 4; g++) {
      int row = w * 32 + g * 8 + r8;
      int cl = cp8 ^ (row & 7);
      gl_lds16(Wm + (size_t)(n0 + row) * K + kk + cl * 8, Ws + (w * 32 + g * 8) * 64);
    }
    __syncthreads();

#pragma unroll
    for (int kidx = 0; kidx < 2; kidx++) {
      bf16x8 bfrag[4], ah[4], al[4];
#pragma unroll
      for (int nt = 0; nt < 4; nt++) {
        int row = wn * 64 + nt * 16 + l16;
        bfrag[nt] =
            *(const bf16x8*)&Ws[row * 64 + (((kidx * 4 + quad) ^ (l16 & 7)) * 8)];
      }
#pragma unroll
      for (int mt = 0; mt < 4; mt++) {
        int row = wm * 64 + mt * 16 + l16;
        int cl0 = kidx * 8 + quad * 2;
        f32x4 fa = *(const f32x4*)&Xs[row * 64 + ((cl0 ^ l16) * 4)];
        f32x4 fb = *(const f32x4*)&Xs[row * 64 + (((cl0 + 1) ^ l16) * 4)];
#pragma unroll
        for (int j = 0; j < 4; j++) {
          bfloat h0 = (bfloat)fa[j], h1 = (bfloat)fb[j];
          ah[mt][j] = h0;
          ah[mt][j + 4] = h1;
          if (split) {
            al[mt][j] = (bfloat)(fa[j] - (float)h0);
            al[mt][j + 4] = (bfloat)(fb[j] - (float)h1);
          }
        }
      }
#pragma unroll
      for (int mt = 0; mt < 4; mt++)
#pragma unroll
        for (int nt = 0; nt < 4; nt++)
          acc[mt][nt] = MFMA_BF16(ah[mt], bfrag[nt], acc[mt][nt]);
      if (split) {
#pragma unroll
        for (int mt = 0; mt < 4; mt++)
#pragma unroll
          for (int nt = 0; nt < 4; nt++)
            acc[mt][nt] = MFMA_BF16(al[mt], bfrag[nt], acc[mt][nt]);
      }
    }
    __syncthreads();
  }

#pragma unroll
  for (int mt = 0; mt < 4; mt++) {
#pragma unroll
    for (int nt = 0; nt < 4; nt++) {
      const int row = m0 + wm * 64 + mt * 16 + quad * 4;
      const int col = n0 + wn * 64 + nt * 16 + l16;
      if (split) {
#pragma unroll
        for (int rg = 0; rg < 4; rg++) {
          float vv = acc[mt][nt][rg] * scale;
          size_t idx = (size_t)(row + rg) * N + col;
          bfloat hh = (bfloat)vv;
          Oh[idx] = hh;
          Ol[idx] = (bfloat)(vv - (float)hh);
        }
      } else {
        // V^T write: 4 consecutive tokens at fixed feature col
        int bb = row >> 11, s = row & (S - 1);
        bf16x4 pk;
#pragma unroll
        for (int rg = 0; rg < 4; rg++) pk[rg] = (bfloat)acc[mt][nt][rg];
        *(bf16x4*)&vtr[(size_t)bb * D * S + (size_t)col * S + s] = pk;
      }
    }
  }
}

// -------- W_O GEMM: 128x64 tile, BK=64, swizzled LDS, fp32 out ------------
__global__ __launch_bounds__(256) void gemm_wo(const bfloat* __restrict__ A,
                                               const bfloat* __restrict__ Wm,
                                               float* __restrict__ Cf) {
  constexpr int K = D;
  constexpr int N = D;
  __shared__ __align__(16) bfloat As[128 * 64];  // 16 KB
  __shared__ __align__(16) bfloat Ws[64 * 64];   // 8 KB

  const int t = threadIdx.x;
  const int w = t >> 6, lane = t & 63;
  const int quad = lane >> 4, l16 = lane & 15;
  const int wm = w >> 1, wn = w & 1;
  const int m0 = blockIdx.y * 128, n0 = blockIdx.x * 64;

  f32x4 acc[4][2] = {};

  const int r8 = lane >> 3, cp8 = lane & 7;

  for (int kk = 0; kk < K; kk += 64) {
#pragma unroll
    for (int g = 0; g < 4; g++) {
      int row = w * 32 + g * 8 + r8;
      int cl = cp8 ^ (row & 7);
      gl_lds16(A + (size_t)(m0 + row) * K + kk + cl * 8, As + (w * 32 + g * 8) * 64);
    }
#pragma unroll
    for (int g = 0; g < 2; g++) {
      int row = w * 16 + g * 8 + r8;
      int cl = cp8 ^ (row & 7);
      gl_lds16(Wm + (size_t)(n0 + row) * K + kk + cl * 8, Ws + (w * 16 + g * 8) * 64);
    }
    __syncthreads();

#pragma unroll
    for (int kidx = 0; kidx < 2; kidx++) {
      bf16x8 bfrag[2], afrag[4];
#pragma unroll
      for (int nt = 0; nt < 2; nt++) {
        int row = wn * 32 + nt * 16 + l16;
        bfrag[nt] =
            *(const bf16x8*)&Ws[row * 64 + (((kidx * 4 + quad) ^ (l16 & 7)) * 8)];
      }
#pragma unroll
      for (int mt = 0; mt < 4; mt++) {
        int row = wm * 64 + mt * 16 + l16;
        afrag[mt] =
            *(const bf16x8*)&As[row * 64 + (((kidx * 4 + quad) ^ (l16 & 7)) * 8)];
      }
#pragma unroll
      for (int mt = 0; mt < 4; mt++)
#pragma unroll
        for (int nt = 0; nt < 2; nt++)
          acc[mt][nt] = MFMA_BF16(afrag[mt], bfrag[nt], acc[mt][nt]);
    }
    __syncthreads();
  }

#pragma unroll
  for (int mt = 0; mt < 4; mt++) {
#pragma unroll
    for (int nt = 0; nt < 2; nt++) {
      const int row = m0 + wm * 64 + mt * 16 + quad * 4;
      const int col = n0 + wn * 32 + nt * 16 + l16;
#pragma unroll
      for (int rg = 0; rg < 4; rg++) Cf[(size_t)(row + rg) * N + col] = acc[mt][nt][rg];
    }
  }
}

// ---------------- flash attention v6: transposed scores -------------------
// S^T = K*Q^T; lane owns one query row (qrow=l16); in-lane softmax with
// ballot-guarded rescale (skips alpha exp2 + 21 muls when no max update).
__global__ __launch_bounds__(256) void flash_kernel(
    const bfloat* __restrict__ qh, const bfloat* __restrict__ ql,
    const bfloat* __restrict__ kh, const bfloat* __restrict__ kl,
    const bfloat* __restrict__ vt, bfloat* __restrict__ outp) {
  __shared__ __align__(16) bfloat Kh[64 * 64];
  __shared__ __align__(16) bfloat Kl[64 * 64];
  __shared__ __align__(16) bfloat Vt[64 * 64];
  __shared__ __align__(16) bfloat Pm[64 * 64];

  const int t = threadIdx.x;
  const int w = t >> 6, lane = t & 63;
  const int quad = lane >> 4, l16 = lane & 15;
  const int b = blockIdx.z, h = blockIdx.y;
  const int q0 = blockIdx.x * 64;
  const size_t base = (size_t)b * S * D + (size_t)h * DH;       // [b][s][n]
  const size_t vbase = (size_t)b * D * S + (size_t)h * DH * S;  // [b][n][s]

  const int ssr = lane >> 3;
  const int spc = lane & 7;

  bf16x8 ones;
#pragma unroll
  for (int j = 0; j < 8; j++) ones[j] = (bfloat)1.f;

  // ---- prologue: stage Q hi/lo through K buffers; B-frags to registers ----
#pragma unroll
  for (int g = 0; g < 2; g++) {
    int r = w * 16 + g * 8 + ssr;
    int c = spc ^ (r & 7);
    int lo = (w * 16 + g * 8) * 64;
    gl_lds16(qh + base + (size_t)(q0 + r) * D + c * 8, Kh + lo);
    gl_lds16(ql + base + (size_t)(q0 + r) * D + c * 8, Kl + lo);
  }
  __syncthreads();
  bf16x8 qhf[2], qlf[2];
  {
    int row = w * 16 + l16;
#pragma unroll
    for (int s2 = 0; s2 < 2; s2++) {
      qhf[s2] = *(const bf16x8*)&Kh[row * 64 + (((s2 * 4 + quad) ^ (l16 & 7)) * 8)];
      qlf[s2] = *(const bf16x8*)&Kl[row * 64 + (((s2 * 4 + quad) ^ (l16 & 7)) * 8)];
    }
  }
  __syncthreads();  // Q frag reads done before first K staging

  f32x4 Oa[4] = {};  // O^T: elem rg -> dim=mt*16+quad*4+rg, qrow=l16
  f32x4 La = {};     // all regs equal: sum_k P (per qrow=l16)
  float m_i = -3.0e38f;

  for (int k0 = 0; k0 < S; k0 += 64) {
#pragma unroll
    for (int g = 0; g < 2; g++) {
      int r = w * 16 + g * 8 + ssr;
      int c = spc ^ (r & 7);
      int lo = (w * 16 + g * 8) * 64;
      gl_lds16(kh + base + (size_t)(k0 + r) * D + c * 8, Kh + lo);
      gl_lds16(kl + base + (size_t)(k0 + r) * D + c * 8, Kl + lo);
      gl_lds16(vt + vbase + (size_t)r * S + k0 + c * 8, Vt + lo);
    }
    __syncthreads();

    // S^T = Kh*Qh + Kl*Qh + Kh*Ql (pre-scaled, log2 domain)
    f32x4 sf[4];
#pragma unroll
    for (int mt = 0; mt < 4; mt++) {
      f32x4 a = {};
      int krow = mt * 16 + l16;
#pragma unroll
      for (int s2 = 0; s2 < 2; s2++) {
        bf16x8 bh = *(const bf16x8*)&Kh[krow * 64 + (((s2 * 4 + quad) ^ (l16 & 7)) * 8)];
        bf16x8 bl = *(const bf16x8*)&Kl[krow * 64 + (((s2 * 4 + quad) ^ (l16 & 7)) * 8)];
        a = MFMA_BF16(bh, qhf[s2], a);
        a = MFMA_BF16(bl, qhf[s2], a);
        a = MFMA_BF16(bh, qlf[s2], a);
      }
      sf[mt] = a;
    }

    // online softmax: lane-scalar state (qrow = l16)
    float mm = sf[0][0];
#pragma unroll
    for (int mt = 0; mt < 4; mt++)
#pragma unroll
      for (int rg = 0; rg < 4; rg++) mm = fmaxf(mm, sf[mt][rg]);
    mm = fmaxf(mm, __shfl_xor(mm, 16, 64));
    mm = fmaxf(mm, __shfl_xor(mm, 32, 64));
    if (__ballot(mm > m_i)) {  // wave-uniform skip when no lane's max moved
      float mnew = fmaxf(m_i, mm);
      float alpha = exp2f(m_i - mnew);
      m_i = mnew;
#pragma unroll
      for (int mt = 0; mt < 4; mt++) Oa[mt] *= alpha;
      La *= alpha;
    }
#pragma unroll
    for (int mt = 0; mt < 4; mt++)
#pragma unroll
      for (int rg = 0; rg < 4; rg++) sf[mt][rg] = exp2f(sf[mt][rg] - m_i);

    // P write: 4 consecutive keys per lane -> b64, 16B-granule swizzle
#pragma unroll
    for (int mt = 0; mt < 4; mt++) {
      bf16x4 pk;
#pragma unroll
      for (int rg = 0; rg < 4; rg++) pk[rg] = (bfloat)sf[mt][rg];
      int g16 = (mt * 2 + (quad >> 1)) ^ (l16 & 7);
      *(bf16x4*)&Pm[(w * 16 + l16) * 64 + g16 * 8 + (quad & 1) * 4] = pk;
    }

    // O^T += V^T * P^T ; La += ones * P^T  (Pm rows wave-private)
#pragma unroll
    for (int s2 = 0; s2 < 2; s2++) {
      bf16x8 pb = *(const bf16x8*)&Pm[(w * 16 + l16) * 64 +
                                      (((s2 * 4 + quad) ^ (l16 & 7)) * 8)];
#pragma unroll
      for (int mt = 0; mt < 4; mt++) {
        int vrow = mt * 16 + l16;
        bf16x8 va = *(const bf16x8*)&Vt[vrow * 64 + (((s2 * 4 + quad) ^ (l16 & 7)) * 8)];
        Oa[mt] = MFMA_BF16(va, pb, Oa[mt]);
      }
      La = MFMA_BF16(ones, pb, La);
    }
    __syncthreads();  // frag reads done before next iteration's staging
  }

  // epilogue: lane owns qrow=l16; 4 consecutive dims per mt -> b64 stores
  float inv = 1.0f / La[0];
  const int qrow = q0 + w * 16 + l16;
#pragma unroll
  for (int mt = 0; mt < 4; mt++) {
    bf16x4 ov;
#pragma unroll
    for (int rg = 0; rg < 4; rg++) ov[rg] = (bfloat)(Oa[mt][rg] * inv);
    *(bf16x4*)&outp[base + (size_t)qrow * D + mt * 16 + quad * 4] = ov;
  }
}

extern "C" void kernel_launch(void* const* d_in, const int* in_sizes, int n_in,
                              void* d_out, int out_size, void* d_ws, size_t ws_size,
                              hipStream_t stream) {
  const float* q_in = (const float*)d_in[0];
  const float* k_in = (const float*)d_in[1];
  const float* v_in = (const float*)d_in[2];
  const float* wq = (const float*)d_in[3];
  const float* wk = (const float*)d_in[4];
  const float* wv = (const float*)d_in[5];
  const float* wo = (const float*)d_in[6];
  float* outp = (float*)d_out;
  char* ws = (char*)d_ws;

  constexpr size_t WBYTES = (size_t)WMAT_N * 2;
  constexpr size_t XBYTES = (size_t)M * D * 2;
  size_t off = 0;
  double* sums = (double*)(ws + off); off += 256;
  bfloat* wqt = (bfloat*)(ws + off); off += WBYTES;
  bfloat* wkt = (bfloat*)(ws + off); off += WBYTES;
  bfloat* wvt = (bfloat*)(ws + off); off += WBYTES;
  bfloat* wot = (bfloat*)(ws + off); off += WBYTES;
  bfloat* qmh = (bfloat*)(ws + off); off += XBYTES;
  bfloat* qml = (bfloat*)(ws + off); off += XBYTES;
  bfloat* kmh = (bfloat*)(ws + off); off += XBYTES;
  bfloat* kml = (bfloat*)(ws + off); off += XBYTES;
  bfloat* vtr = (bfloat*)(ws + off); off += XBYTES;  // V^T [B][D][S]
  bfloat* attn = (bfloat*)(ws + off); off += XBYTES;

  hipMemsetAsync(sums, 0, 4 * sizeof(double), stream);
  absum_kernel<<<dim3(128, 4), 256, 0, stream>>>(wq, wk, wv, wo, sums);
  tern_kernel<<<dim3(128, 4), 256, 0, stream>>>(wq, wk, wv, wo, wqt, wkt, wvt, wot, sums);
  qkv_gemm<<<dim3(D / 128, M / 128, 3), 256, 0, stream>>>(
      q_in, k_in, v_in, wqt, wkt, wvt, qmh, qml, kmh, kml, vtr);
  flash_kernel<<<dim3(S / 64, H, B), 256, 0, stream>>>(qmh, qml, kmh, kml, vtr, attn);
  gemm_wo<<<dim3(D / 64, M / 128), 256, 0, stream>>>(attn, wot, outp);
}

// Round 7
// 299.446 us; speedup vs baseline: 1.0473x; 1.0473x over previous
//
#include <hip/hip_runtime.h>
#include <cstdint>
#include <cstddef>

typedef __bf16 bfloat;
typedef __bf16 bf16x8 __attribute__((ext_vector_type(8)));
typedef __bf16 bf16x4 __attribute__((ext_vector_type(4)));
typedef float  f32x4  __attribute__((ext_vector_type(4)));

static constexpr int D  = 1024;
static constexpr int S  = 2048;
static constexpr int B  = 2;
static constexpr int H  = 16;
static constexpr int DH = 64;
static constexpr int M  = B * S;
static constexpr int WMAT_N = 1024 * 1024;

#define MFMA_BF16(a, b, c) __builtin_amdgcn_mfma_f32_16x16x32_bf16((a), (b), (c), 0, 0, 0)

__device__ __forceinline__ void gl_lds16(const void* g, void* l) {
  __builtin_amdgcn_global_load_lds(
      (const __attribute__((address_space(1))) void*)g,
      (__attribute__((address_space(3))) void*)l, 16, 0, 0);
}

// ---------------- abs-sum reduce in f64 ----------------
__global__ void absum_kernel(const float* __restrict__ w0, const float* __restrict__ w1,
                             const float* __restrict__ w2, const float* __restrict__ w3,
                             double* __restrict__ sums) {
  int z = blockIdx.y;
  const float* w = (z == 0) ? w0 : (z == 1) ? w1 : (z == 2) ? w2 : w3;
  const float4* w4 = (const float4*)w;
  double s = 0.0;
  for (int i = blockIdx.x * blockDim.x + threadIdx.x; i < (WMAT_N / 4);
       i += gridDim.x * blockDim.x) {
    float4 v = w4[i];
    s += (double)fabsf(v.x) + (double)fabsf(v.y) + (double)fabsf(v.z) + (double)fabsf(v.w);
  }
  for (int off = 1; off < 64; off <<= 1) s += __shfl_xor(s, off, 64);
  __shared__ double ps[4];
  if ((threadIdx.x & 63) == 0) ps[threadIdx.x >> 6] = s;
  __syncthreads();
  if (threadIdx.x == 0) atomicAdd(&sums[z], ps[0] + ps[1] + ps[2] + ps[3]);
}

// ---------------- ternarize -> bf16 ----------------
__global__ void tern_kernel(const float* __restrict__ w0, const float* __restrict__ w1,
                            const float* __restrict__ w2, const float* __restrict__ w3,
                            bfloat* __restrict__ o0, bfloat* __restrict__ o1,
                            bfloat* __restrict__ o2, bfloat* __restrict__ o3,
                            const double* __restrict__ sums) {
  int z = blockIdx.y;
  const float* w = (z == 0) ? w0 : (z == 1) ? w1 : (z == 2) ? w2 : w3;
  bfloat* o = (z == 0) ? o0 : (z == 1) ? o1 : (z == 2) ? o2 : o3;
  double thr = sums[z] * (1.0 / (double)WMAT_N);
  const float4* w4 = (const float4*)w;
  for (int i = blockIdx.x * blockDim.x + threadIdx.x; i < (WMAT_N / 4);
       i += gridDim.x * blockDim.x) {
    float4 v = w4[i];
    bf16x4 r;
    r[0] = (bfloat)(((double)fabsf(v.x) > thr) ? (v.x > 0.f ? 1.f : -1.f) : 0.f);
    r[1] = (bfloat)(((double)fabsf(v.y) > thr) ? (v.y > 0.f ? 1.f : -1.f) : 0.f);
    r[2] = (bfloat)(((double)fabsf(v.z) > thr) ? (v.z > 0.f ? 1.f : -1.f) : 0.f);
    r[3] = (bfloat)(((double)fabsf(v.w) > thr) ? (v.w > 0.f ? 1.f : -1.f) : 0.f);
    *(bf16x4*)&o[(size_t)i * 4] = r;
  }
}

// ------------- fp32 -> bf16 hi (+ lo residual) for q,k,v in one launch -----
__global__ void splitcvt3_kernel(const float* __restrict__ qx, const float* __restrict__ kx,
                                 const float* __restrict__ vx, bfloat* __restrict__ qhi,
                                 bfloat* __restrict__ qlo, bfloat* __restrict__ khi,
                                 bfloat* __restrict__ klo, bfloat* __restrict__ vhi) {
  int z = blockIdx.y;
  const float* x = (z == 0) ? qx : (z == 1) ? kx : vx;
  bfloat* hi = (z == 0) ? qhi : (z == 1) ? khi : vhi;
  bfloat* lo = (z == 0) ? qlo : (z == 1) ? klo : nullptr;
  const int n4 = M * D / 4;
  const float4* x4 = (const float4*)x;
  for (int i = blockIdx.x * blockDim.x + threadIdx.x; i < n4; i += gridDim.x * blockDim.x) {
    float4 v = x4[i];
    bf16x4 h;
    h[0] = (bfloat)v.x; h[1] = (bfloat)v.y; h[2] = (bfloat)v.z; h[3] = (bfloat)v.w;
    *(bf16x4*)&hi[(size_t)i * 4] = h;
    if (z < 2) {
      bf16x4 l;
      l[0] = (bfloat)(v.x - (float)h[0]);
      l[1] = (bfloat)(v.y - (float)h[1]);
      l[2] = (bfloat)(v.z - (float)h[2]);
      l[3] = (bfloat)(v.w - (float)h[3]);
      *(bf16x4*)&lo[(size_t)i * 4] = l;
    }
  }
}

// -------- fused q/k/v projection: blockIdx.z selects matrix ---------------
// 128x128 tile, BK=32, bf16-staged, XOR-swizzled LDS (2-way-clean b128 reads:
// phys_chunk = logical ^ ((row>>1)&3)). v-branch writes V^T [B][D][S].
__global__ __launch_bounds__(256) void qkv_gemm(
    const bfloat* __restrict__ xqh, const bfloat* __restrict__ xql,
    const bfloat* __restrict__ xkh, const bfloat* __restrict__ xkl,
    const bfloat* __restrict__ xvh, const bfloat* __restrict__ wqt,
    const bfloat* __restrict__ wkt, const bfloat* __restrict__ wvt,
    bfloat* __restrict__ qmh, bfloat* __restrict__ qml,
    bfloat* __restrict__ kmh, bfloat* __restrict__ kml, bfloat* __restrict__ vtr) {
  constexpr int K = D;
  constexpr int N = D;
  __shared__ __align__(16) bfloat As0[128 * 32];
  __shared__ __align__(16) bfloat As1[128 * 32];
  __shared__ __align__(16) bfloat Ws[128 * 32];

  const int z = blockIdx.z;
  const bfloat *A0, *A1 = nullptr, *Wm;
  bfloat *Oh = nullptr, *Ol = nullptr;
  float scale = 1.f;
  bool split;
  if (z == 0) {
    A0 = xqh; A1 = xql; Wm = wqt; Oh = qmh; Ol = qml;
    scale = 0.18033688f;  // 1/sqrt(64) * log2(e), folded out of flash
    split = true;
  } else if (z == 1) {
    A0 = xkh; A1 = xkl; Wm = wkt; Oh = kmh; Ol = kml; split = true;
  } else {
    A0 = xvh; Wm = wvt; split = false;
  }

  const int t = threadIdx.x;
  const int w = t >> 6, lane = t & 63;
  const int quad = lane >> 4, l16 = lane & 15;
  const int wm = w >> 1, wn = w & 1;
  const int m0 = blockIdx.y * 128, n0 = blockIdx.x * 128;

  f32x4 acc[4][4] = {};

  const int sr = t >> 2;                       // staging row within 64 (global row index)
  const int cp = t & 3;                        // physical 16B chunk slot
  const int cla = cp ^ ((sr >> 1) & 3);        // logical chunk for rows sr
  const int clb = cp ^ (((sr + 64) >> 1) & 3); // logical chunk for rows sr+64

  const bfloat* pA0a = A0 + (size_t)(m0 + sr) * K + cla * 8;
  const bfloat* pA0b = A0 + (size_t)(m0 + 64 + sr) * K + clb * 8;
  const bfloat* pA1a = split ? A1 + (size_t)(m0 + sr) * K + cla * 8 : nullptr;
  const bfloat* pA1b = split ? A1 + (size_t)(m0 + 64 + sr) * K + clb * 8 : nullptr;
  const bfloat* pWa = Wm + (size_t)(n0 + sr) * K + cla * 8;
  const bfloat* pWb = Wm + (size_t)(n0 + 64 + sr) * K + clb * 8;

  for (int kk = 0; kk < K; kk += 32) {
    gl_lds16(pA0a + kk, As0 + w * 512);
    gl_lds16(pA0b + kk, As0 + 2048 + w * 512);
    if (split) {
      gl_lds16(pA1a + kk, As1 + w * 512);
      gl_lds16(pA1b + kk, As1 + 2048 + w * 512);
    }
    gl_lds16(pWa + kk, Ws + w * 512);
    gl_lds16(pWb + kk, Ws + 2048 + w * 512);
    __syncthreads();

    bf16x8 bfrag[4], afrag[4];
#pragma unroll
    for (int nt = 0; nt < 4; nt++) {
      int r = wn * 64 + nt * 16 + l16;
      bfrag[nt] = *(const bf16x8*)&Ws[r * 32 + ((quad ^ ((r >> 1) & 3)) * 8)];
    }
#pragma unroll
    for (int mt = 0; mt < 4; mt++) {
      int r = wm * 64 + mt * 16 + l16;
      afrag[mt] = *(const bf16x8*)&As0[r * 32 + ((quad ^ ((r >> 1) & 3)) * 8)];
    }
#pragma unroll
    for (int mt = 0; mt < 4; mt++)
#pragma unroll
      for (int nt = 0; nt < 4; nt++)
        acc[mt][nt] = MFMA_BF16(afrag[mt], bfrag[nt], acc[mt][nt]);
    if (split) {
#pragma unroll
      for (int mt = 0; mt < 4; mt++) {
        int r = wm * 64 + mt * 16 + l16;
        afrag[mt] = *(const bf16x8*)&As1[r * 32 + ((quad ^ ((r >> 1) & 3)) * 8)];
      }
#pragma unroll
      for (int mt = 0; mt < 4; mt++)
#pragma unroll
        for (int nt = 0; nt < 4; nt++)
          acc[mt][nt] = MFMA_BF16(afrag[mt], bfrag[nt], acc[mt][nt]);
    }
    __syncthreads();
  }

#pragma unroll
  for (int mt = 0; mt < 4; mt++) {
#pragma unroll
    for (int nt = 0; nt < 4; nt++) {
      const int row = m0 + wm * 64 + mt * 16 + quad * 4;
      const int col = n0 + wn * 64 + nt * 16 + l16;
      if (split) {
#pragma unroll
        for (int rg = 0; rg < 4; rg++) {
          float vv = acc[mt][nt][rg] * scale;
          size_t idx = (size_t)(row + rg) * N + col;
          bfloat hh = (bfloat)vv;
          Oh[idx] = hh;
          Ol[idx] = (bfloat)(vv - (float)hh);
        }
      } else {
        // V^T write: 4 consecutive tokens at fixed feature col
        int bb = row >> 11, s = row & (S - 1);
        bf16x4 pk;
#pragma unroll
        for (int rg = 0; rg < 4; rg++) pk[rg] = (bfloat)acc[mt][nt][rg];
        *(bf16x4*)&vtr[(size_t)bb * D * S + (size_t)col * S + s] = pk;
      }
    }
  }
}

// -------- W_O GEMM: 128x64 tile, BK=32, swizzled LDS, fp32 out ------------
__global__ __launch_bounds__(256) void gemm_wo(const bfloat* __restrict__ A,
                                               const bfloat* __restrict__ Wm,
                                               float* __restrict__ Cf) {
  constexpr int K = D;
  constexpr int N = D;
  __shared__ __align__(16) bfloat As[128 * 32];
  __shared__ __align__(16) bfloat Ws[64 * 32];

  const int t = threadIdx.x;
  const int w = t >> 6, lane = t & 63;
  const int quad = lane >> 4, l16 = lane & 15;
  const int wm = w >> 1, wn = w & 1;
  const int m0 = blockIdx.y * 128, n0 = blockIdx.x * 64;

  f32x4 acc[4][2] = {};

  const int sr = t >> 2;
  const int cp = t & 3;
  const int cla = cp ^ ((sr >> 1) & 3);
  const int clb = cp ^ (((sr + 64) >> 1) & 3);
  const bfloat* pAa = A + (size_t)(m0 + sr) * K + cla * 8;
  const bfloat* pAb = A + (size_t)(m0 + 64 + sr) * K + clb * 8;
  const bfloat* pW = Wm + (size_t)(n0 + sr) * K + cla * 8;

  for (int kk = 0; kk < K; kk += 32) {
    gl_lds16(pAa + kk, As + w * 512);
    gl_lds16(pAb + kk, As + 2048 + w * 512);
    gl_lds16(pW + kk, Ws + w * 512);
    __syncthreads();

    bf16x8 bfrag[2], afrag[4];
#pragma unroll
    for (int nt = 0; nt < 2; nt++) {
      int r = wn * 32 + nt * 16 + l16;
      bfrag[nt] = *(const bf16x8*)&Ws[r * 32 + ((quad ^ ((r >> 1) & 3)) * 8)];
    }
#pragma unroll
    for (int mt = 0; mt < 4; mt++) {
      int r = wm * 64 + mt * 16 + l16;
      afrag[mt] = *(const bf16x8*)&As[r * 32 + ((quad ^ ((r >> 1) & 3)) * 8)];
    }
#pragma unroll
    for (int mt = 0; mt < 4; mt++)
#pragma unroll
      for (int nt = 0; nt < 2; nt++)
        acc[mt][nt] = MFMA_BF16(afrag[mt], bfrag[nt], acc[mt][nt]);
    __syncthreads();
  }

#pragma unroll
  for (int mt = 0; mt < 4; mt++) {
#pragma unroll
    for (int nt = 0; nt < 2; nt++) {
      const int row = m0 + wm * 64 + mt * 16 + quad * 4;
      const int col = n0 + wn * 32 + nt * 16 + l16;
#pragma unroll
      for (int rg = 0; rg < 4; rg++) Cf[(size_t)(row + rg) * N + col] = acc[mt][nt][rg];
    }
  }
}

// ---------------- flash attention v6: transposed scores -------------------
// S^T = K*Q^T; lane owns one query row (qrow=l16); in-lane softmax with
// ballot-guarded rescale.
__global__ __launch_bounds__(256) void flash_kernel(
    const bfloat* __restrict__ qh, const bfloat* __restrict__ ql,
    const bfloat* __restrict__ kh, const bfloat* __restrict__ kl,
    const bfloat* __restrict__ vt, bfloat* __restrict__ outp) {
  __shared__ __align__(16) bfloat Kh[64 * 64];
  __shared__ __align__(16) bfloat Kl[64 * 64];
  __shared__ __align__(16) bfloat Vt[64 * 64];
  __shared__ __align__(16) bfloat Pm[64 * 64];

  const int t = threadIdx.x;
  const int w = t >> 6, lane = t & 63;
  const int quad = lane >> 4, l16 = lane & 15;
  const int b = blockIdx.z, h = blockIdx.y;
  const int q0 = blockIdx.x * 64;
  const size_t base = (size_t)b * S * D + (size_t)h * DH;       // [b][s][n]
  const size_t vbase = (size_t)b * D * S + (size_t)h * DH * S;  // [b][n][s]

  const int ssr = lane >> 3;
  const int spc = lane & 7;

  bf16x8 ones;
#pragma unroll
  for (int j = 0; j < 8; j++) ones[j] = (bfloat)1.f;

  // ---- prologue: stage Q hi/lo through K buffers; B-frags to registers ----
#pragma unroll
  for (int g = 0; g < 2; g++) {
    int r = w * 16 + g * 8 + ssr;
    int c = spc ^ (r & 7);
    int lo = (w * 16 + g * 8) * 64;
    gl_lds16(qh + base + (size_t)(q0 + r) * D + c * 8, Kh + lo);
    gl_lds16(ql + base + (size_t)(q0 + r) * D + c * 8, Kl + lo);
  }
  __syncthreads();
  bf16x8 qhf[2], qlf[2];
  {
    int row = w * 16 + l16;
#pragma unroll
    for (int s2 = 0; s2 < 2; s2++) {
      qhf[s2] = *(const bf16x8*)&Kh[row * 64 + (((s2 * 4 + quad) ^ (l16 & 7)) * 8)];
      qlf[s2] = *(const bf16x8*)&Kl[row * 64 + (((s2 * 4 + quad) ^ (l16 & 7)) * 8)];
    }
  }
  __syncthreads();  // Q frag reads done before first K staging

  f32x4 Oa[4] = {};  // O^T: elem rg -> dim=mt*16+quad*4+rg, qrow=l16
  f32x4 La = {};     // all regs equal: sum_k P (per qrow=l16)
  float m_i = -3.0e38f;

  for (int k0 = 0; k0 < S; k0 += 64) {
#pragma unroll
    for (int g = 0; g < 2; g++) {
      int r = w * 16 + g * 8 + ssr;
      int c = spc ^ (r & 7);
      int lo = (w * 16 + g * 8) * 64;
      gl_lds16(kh + base + (size_t)(k0 + r) * D + c * 8, Kh + lo);
      gl_lds16(kl + base + (size_t)(k0 + r) * D + c * 8, Kl + lo);
      gl_lds16(vt + vbase + (size_t)r * S + k0 + c * 8, Vt + lo);
    }
    __syncthreads();

    // S^T = Kh*Qh + Kl*Qh + Kh*Ql (pre-scaled, log2 domain)
    f32x4 sf[4];
#pragma unroll
    for (int mt = 0; mt < 4; mt++) {
      f32x4 a = {};
      int krow = mt * 16 + l16;
#pragma unroll
      for (int s2 = 0; s2 < 2; s2++) {
        bf16x8 bh = *(const bf16x8*)&Kh[krow * 64 + (((s2 * 4 + quad) ^ (l16 & 7)) * 8)];
        bf16x8 bl = *(const bf16x8*)&Kl[krow * 64 + (((s2 * 4 + quad) ^ (l16 & 7)) * 8)];
        a = MFMA_BF16(bh, qhf[s2], a);
        a = MFMA_BF16(bl, qhf[s2], a);
        a = MFMA_BF16(bh, qlf[s2], a);
      }
      sf[mt] = a;
    }

    // online softmax: lane-scalar state (qrow = l16)
    float mm = sf[0][0];
#pragma unroll
    for (int mt = 0; mt < 4; mt++)
#pragma unroll
      for (int rg = 0; rg < 4; rg++) mm = fmaxf(mm, sf[mt][rg]);
    mm = fmaxf(mm, __shfl_xor(mm, 16, 64));
    mm = fmaxf(mm, __shfl_xor(mm, 32, 64));
    if (__ballot(mm > m_i)) {  // wave-uniform skip when no lane's max moved
      float mnew = fmaxf(m_i, mm);
      float alpha = exp2f(m_i - mnew);
      m_i = mnew;
#pragma unroll
      for (int mt = 0; mt < 4; mt++) Oa[mt] *= alpha;
      La *= alpha;
    }
#pragma unroll
    for (int mt = 0; mt < 4; mt++)
#pragma unroll
      for (int rg = 0; rg < 4; rg++) sf[mt][rg] = exp2f(sf[mt][rg] - m_i);

    // P write: 4 consecutive keys per lane -> b64, 16B-granule swizzle
#pragma unroll
    for (int mt = 0; mt < 4; mt++) {
      bf16x4 pk;
#pragma unroll
      for (int rg = 0; rg < 4; rg++) pk[rg] = (bfloat)sf[mt][rg];
      int g16 = (mt * 2 + (quad >> 1)) ^ (l16 & 7);
      *(bf16x4*)&Pm[(w * 16 + l16) * 64 + g16 * 8 + (quad & 1) * 4] = pk;
    }

    // O^T += V^T * P^T ; La += ones * P^T  (Pm rows wave-private)
#pragma unroll
    for (int s2 = 0; s2 < 2; s2++) {
      bf16x8 pb = *(const bf16x8*)&Pm[(w * 16 + l16) * 64 +
                                      (((s2 * 4 + quad) ^ (l16 & 7)) * 8)];
#pragma unroll
      for (int mt = 0; mt < 4; mt++) {
        int vrow = mt * 16 + l16;
        bf16x8 va = *(const bf16x8*)&Vt[vrow * 64 + (((s2 * 4 + quad) ^ (l16 & 7)) * 8)];
        Oa[mt] = MFMA_BF16(va, pb, Oa[mt]);
      }
      La = MFMA_BF16(ones, pb, La);
    }
    __syncthreads();  // frag reads done before next iteration's staging
  }

  // epilogue: lane owns qrow=l16; 4 consecutive dims per mt -> b64 stores
  float inv = 1.0f / La[0];
  const int qrow = q0 + w * 16 + l16;
#pragma unroll
  for (int mt = 0; mt < 4; mt++) {
    bf16x4 ov;
#pragma unroll
    for (int rg = 0; rg < 4; rg++) ov[rg] = (bfloat)(Oa[mt][rg] * inv);
    *(bf16x4*)&outp[base + (size_t)qrow * D + mt * 16 + quad * 4] = ov;
  }
}

extern "C" void kernel_launch(void* const* d_in, const int* in_sizes, int n_in,
                              void* d_out, int out_size, void* d_ws, size_t ws_size,
                              hipStream_t stream) {
  const float* q_in = (const float*)d_in[0];
  const float* k_in = (const float*)d_in[1];
  const float* v_in = (const float*)d_in[2];
  const float* wq = (const float*)d_in[3];
  const float* wk = (const float*)d_in[4];
  const float* wv = (const float*)d_in[5];
  const float* wo = (const float*)d_in[6];
  float* outp = (float*)d_out;
  char* ws = (char*)d_ws;

  constexpr size_t WBYTES = (size_t)WMAT_N * 2;
  constexpr size_t XBYTES = (size_t)M * D * 2;
  size_t off = 0;
  double* sums = (double*)(ws + off); off += 256;
  bfloat* wqt = (bfloat*)(ws + off); off += WBYTES;
  bfloat* wkt = (bfloat*)(ws + off); off += WBYTES;
  bfloat* wvt = (bfloat*)(ws + off); off += WBYTES;
  bfloat* wot = (bfloat*)(ws + off); off += WBYTES;
  bfloat* xqh = (bfloat*)(ws + off); off += XBYTES;
  bfloat* xql = (bfloat*)(ws + off); off += XBYTES;
  bfloat* xkh = (bfloat*)(ws + off); off += XBYTES;
  bfloat* xkl = (bfloat*)(ws + off); off += XBYTES;
  bfloat* xvh = (bfloat*)(ws + off); off += XBYTES;
  bfloat* qmh = (bfloat*)(ws + off); off += XBYTES;
  bfloat* qml = (bfloat*)(ws + off); off += XBYTES;
  bfloat* kmh = (bfloat*)(ws + off); off += XBYTES;
  bfloat* kml = (bfloat*)(ws + off); off += XBYTES;
  bfloat* vtr = (bfloat*)(ws + off); off += XBYTES;  // V^T [B][D][S]
  bfloat* attn = xqh;  // dead after q projection

  hipMemsetAsync(sums, 0, 4 * sizeof(double), stream);
  absum_kernel<<<dim3(128, 4), 256, 0, stream>>>(wq, wk, wv, wo, sums);
  tern_kernel<<<dim3(128, 4), 256, 0, stream>>>(wq, wk, wv, wo, wqt, wkt, wvt, wot, sums);
  splitcvt3_kernel<<<dim3(512, 3), 256, 0, stream>>>(q_in, k_in, v_in, xqh, xql, xkh, xkl, xvh);
  qkv_gemm<<<dim3(D / 128, M / 128, 3), 256, 0, stream>>>(
      xqh, xql, xkh, xkl, xvh, wqt, wkt, wvt, qmh, qml, kmh, kml, vtr);
  flash_kernel<<<dim3(S / 64, H, B), 256, 0, stream>>>(qmh, qml, kmh, kml, vtr, attn);
  gemm_wo<<<dim3(D / 64, M / 128), 256, 0, stream>>>(attn, wot, outp);
}

// Round 8
// 294.334 us; speedup vs baseline: 1.0655x; 1.0174x over previous
//
#include <hip/hip_runtime.h>
#include <cstdint>
#include <cstddef>

typedef __bf16 bfloat;
typedef __bf16 bf16x8 __attribute__((ext_vector_type(8)));
typedef __bf16 bf16x4 __attribute__((ext_vector_type(4)));
typedef float  f32x4  __attribute__((ext_vector_type(4)));

static constexpr int D  = 1024;
static constexpr int S  = 2048;
static constexpr int B  = 2;
static constexpr int H  = 16;
static constexpr int DH = 64;
static constexpr int M  = B * S;
static constexpr int WMAT_N = 1024 * 1024;

#define MFMA_BF16(a, b, c) __builtin_amdgcn_mfma_f32_16x16x32_bf16((a), (b), (c), 0, 0, 0)

__device__ __forceinline__ void gl_lds16(const void* g, void* l) {
  __builtin_amdgcn_global_load_lds(
      (const __attribute__((address_space(1))) void*)g,
      (__attribute__((address_space(3))) void*)l, 16, 0, 0);
}

// ---- prep: y<4 -> f64 abs-sum of weight z ; y in 4..6 -> split-convert ----
// Fuses the two independent bandwidth-bound preprocessing passes into one
// launch so they share the memory pipes instead of running serially.
__global__ void prep_kernel(const float* __restrict__ w0, const float* __restrict__ w1,
                            const float* __restrict__ w2, const float* __restrict__ w3,
                            const float* __restrict__ qx, const float* __restrict__ kx,
                            const float* __restrict__ vx, bfloat* __restrict__ qhi,
                            bfloat* __restrict__ qlo, bfloat* __restrict__ khi,
                            bfloat* __restrict__ klo, bfloat* __restrict__ vhi,
                            double* __restrict__ sums) {
  const int y = blockIdx.y;
  if (y < 4) {
    const float* w = (y == 0) ? w0 : (y == 1) ? w1 : (y == 2) ? w2 : w3;
    const float4* w4 = (const float4*)w;
    double s = 0.0;
    for (int i = blockIdx.x * blockDim.x + threadIdx.x; i < (WMAT_N / 4);
         i += gridDim.x * blockDim.x) {
      float4 v = w4[i];
      s += (double)fabsf(v.x) + (double)fabsf(v.y) + (double)fabsf(v.z) + (double)fabsf(v.w);
    }
    for (int off = 1; off < 64; off <<= 1) s += __shfl_xor(s, off, 64);
    __shared__ double ps[4];
    if ((threadIdx.x & 63) == 0) ps[threadIdx.x >> 6] = s;
    __syncthreads();
    if (threadIdx.x == 0) atomicAdd(&sums[y], ps[0] + ps[1] + ps[2] + ps[3]);
  } else {
    const int z = y - 4;
    const float* x = (z == 0) ? qx : (z == 1) ? kx : vx;
    bfloat* hi = (z == 0) ? qhi : (z == 1) ? khi : vhi;
    bfloat* lo = (z == 0) ? qlo : (z == 1) ? klo : nullptr;
    const int n8 = M * D / 8;
    const float4* x4 = (const float4*)x;
    for (int i = blockIdx.x * blockDim.x + threadIdx.x; i < n8;
         i += gridDim.x * blockDim.x) {
      float4 a = x4[2 * i], b = x4[2 * i + 1];
      float f[8] = {a.x, a.y, a.z, a.w, b.x, b.y, b.z, b.w};
      bf16x8 h;
#pragma unroll
      for (int j = 0; j < 8; j++) h[j] = (bfloat)f[j];
      *(bf16x8*)&hi[(size_t)i * 8] = h;
      if (z < 2) {
        bf16x8 l;
#pragma unroll
        for (int j = 0; j < 8; j++) l[j] = (bfloat)(f[j] - (float)h[j]);
        *(bf16x8*)&lo[(size_t)i * 8] = l;
      }
    }
  }
}

// ---------------- ternarize -> bf16 ----------------
__global__ void tern_kernel(const float* __restrict__ w0, const float* __restrict__ w1,
                            const float* __restrict__ w2, const float* __restrict__ w3,
                            bfloat* __restrict__ o0, bfloat* __restrict__ o1,
                            bfloat* __restrict__ o2, bfloat* __restrict__ o3,
                            const double* __restrict__ sums) {
  int z = blockIdx.y;
  const float* w = (z == 0) ? w0 : (z == 1) ? w1 : (z == 2) ? w2 : w3;
  bfloat* o = (z == 0) ? o0 : (z == 1) ? o1 : (z == 2) ? o2 : o3;
  double thr = sums[z] * (1.0 / (double)WMAT_N);
  const float4* w4 = (const float4*)w;
  for (int i = blockIdx.x * blockDim.x + threadIdx.x; i < (WMAT_N / 4);
       i += gridDim.x * blockDim.x) {
    float4 v = w4[i];
    bf16x4 r;
    r[0] = (bfloat)(((double)fabsf(v.x) > thr) ? (v.x > 0.f ? 1.f : -1.f) : 0.f);
    r[1] = (bfloat)(((double)fabsf(v.y) > thr) ? (v.y > 0.f ? 1.f : -1.f) : 0.f);
    r[2] = (bfloat)(((double)fabsf(v.z) > thr) ? (v.z > 0.f ? 1.f : -1.f) : 0.f);
    r[3] = (bfloat)(((double)fabsf(v.w) > thr) ? (v.w > 0.f ? 1.f : -1.f) : 0.f);
    *(bf16x4*)&o[(size_t)i * 4] = r;
  }
}

// -------- fused q/k/v projection: 128x128 tile, BK=64 (half the barrier
// drains of BK=32 at the same 3 blocks/CU: 48 KB LDS). Rows are 64 bf16;
// swizzle phys_chunk = logical ^ (row&7) -> 2-way-clean b128 reads.
// Accumulation order preserved vs BK=32: per 32-k sub-chunk, hi then lo.
__global__ __launch_bounds__(256) void qkv_gemm(
    const bfloat* __restrict__ xqh, const bfloat* __restrict__ xql,
    const bfloat* __restrict__ xkh, const bfloat* __restrict__ xkl,
    const bfloat* __restrict__ xvh, const bfloat* __restrict__ wqt,
    const bfloat* __restrict__ wkt, const bfloat* __restrict__ wvt,
    bfloat* __restrict__ qmh, bfloat* __restrict__ qml,
    bfloat* __restrict__ kmh, bfloat* __restrict__ kml, bfloat* __restrict__ vtr) {
  constexpr int K = D;
  constexpr int N = D;
  __shared__ __align__(16) bfloat As0[128 * 64];
  __shared__ __align__(16) bfloat As1[128 * 64];
  __shared__ __align__(16) bfloat Ws[128 * 64];

  const int z = blockIdx.z;
  const bfloat *A0, *A1 = nullptr, *Wm;
  bfloat *Oh = nullptr, *Ol = nullptr;
  float scale = 1.f;
  bool split;
  if (z == 0) {
    A0 = xqh; A1 = xql; Wm = wqt; Oh = qmh; Ol = qml;
    scale = 0.18033688f;  // 1/sqrt(64) * log2(e), folded out of flash
    split = true;
  } else if (z == 1) {
    A0 = xkh; A1 = xkl; Wm = wkt; Oh = kmh; Ol = kml; split = true;
  } else {
    A0 = xvh; Wm = wvt; split = false;
  }

  const int t = threadIdx.x;
  const int w = t >> 6, lane = t & 63;
  const int quad = lane >> 4, l16 = lane & 15;
  const int wm = w >> 1, wn = w & 1;
  const int m0 = blockIdx.y * 128, n0 = blockIdx.x * 128;

  f32x4 acc[4][4] = {};

  // staging: per gl_lds16 call a wave covers 8 rows x 8 chunks (16B each)
  const int srr = lane >> 3;  // row within 8-row group
  const int spc = lane & 7;   // physical chunk

  for (int kk = 0; kk < K; kk += 64) {
#pragma unroll
    for (int g = 0; g < 4; g++) {
      int row = w * 32 + g * 8 + srr;
      int cl = spc ^ (row & 7);
      int lo = (w * 32 + g * 8) * 64;
      gl_lds16(A0 + (size_t)(m0 + row) * K + kk + cl * 8, As0 + lo);
      if (split) gl_lds16(A1 + (size_t)(m0 + row) * K + kk + cl * 8, As1 + lo);
      gl_lds16(Wm + (size_t)(n0 + row) * K + kk + cl * 8, Ws + lo);
    }
    __syncthreads();

#pragma unroll
    for (int kidx = 0; kidx < 2; kidx++) {
      bf16x8 bfrag[4], afrag[4];
#pragma unroll
      for (int nt = 0; nt < 4; nt++) {
        int r = wn * 64 + nt * 16 + l16;
        bfrag[nt] = *(const bf16x8*)&Ws[r * 64 + (((kidx * 4 + quad) ^ (r & 7)) * 8)];
      }
#pragma unroll
      for (int mt = 0; mt < 4; mt++) {
        int r = wm * 64 + mt * 16 + l16;
        afrag[mt] = *(const bf16x8*)&As0[r * 64 + (((kidx * 4 + quad) ^ (r & 7)) * 8)];
      }
#pragma unroll
      for (int mt = 0; mt < 4; mt++)
#pragma unroll
        for (int nt = 0; nt < 4; nt++)
          acc[mt][nt] = MFMA_BF16(afrag[mt], bfrag[nt], acc[mt][nt]);
      if (split) {
#pragma unroll
        for (int mt = 0; mt < 4; mt++) {
          int r = wm * 64 + mt * 16 + l16;
          afrag[mt] = *(const bf16x8*)&As1[r * 64 + (((kidx * 4 + quad) ^ (r & 7)) * 8)];
        }
#pragma unroll
        for (int mt = 0; mt < 4; mt++)
#pragma unroll
          for (int nt = 0; nt < 4; nt++)
            acc[mt][nt] = MFMA_BF16(afrag[mt], bfrag[nt], acc[mt][nt]);
      }
    }
    __syncthreads();
  }

#pragma unroll
  for (int mt = 0; mt < 4; mt++) {
#pragma unroll
    for (int nt = 0; nt < 4; nt++) {
      const int row = m0 + wm * 64 + mt * 16 + quad * 4;
      const int col = n0 + wn * 64 + nt * 16 + l16;
      if (split) {
#pragma unroll
        for (int rg = 0; rg < 4; rg++) {
          float vv = acc[mt][nt][rg] * scale;
          size_t idx = (size_t)(row + rg) * N + col;
          bfloat hh = (bfloat)vv;
          Oh[idx] = hh;
          Ol[idx] = (bfloat)(vv - (float)hh);
        }
      } else {
        // V^T write: 4 consecutive tokens at fixed feature col
        int bb = row >> 11, s = row & (S - 1);
        bf16x4 pk;
#pragma unroll
        for (int rg = 0; rg < 4; rg++) pk[rg] = (bfloat)acc[mt][nt][rg];
        *(bf16x4*)&vtr[(size_t)bb * D * S + (size_t)col * S + s] = pk;
      }
    }
  }
}

// -------- W_O GEMM: 64x64 tile, BK=32, 1024 blocks = 4/CU, fp32 out -------
__global__ __launch_bounds__(256, 4) void gemm_wo(const bfloat* __restrict__ A,
                                                  const bfloat* __restrict__ Wm,
                                                  float* __restrict__ Cf) {
  constexpr int K = D;
  constexpr int N = D;
  __shared__ __align__(16) bfloat As[64 * 32];
  __shared__ __align__(16) bfloat Ws[64 * 32];

  const int t = threadIdx.x;
  const int w = t >> 6, lane = t & 63;
  const int quad = lane >> 4, l16 = lane & 15;
  const int wm = w >> 1, wn = w & 1;
  const int m0 = blockIdx.y * 64, n0 = blockIdx.x * 64;

  f32x4 acc[2][2] = {};

  const int sr = w * 16 + (lane >> 2);
  const int sc = (lane & 3) ^ ((sr >> 1) & 3);

  const bfloat* pA = A + (size_t)(m0 + sr) * K + sc * 8;
  const bfloat* pW = Wm + (size_t)(n0 + sr) * K + sc * 8;
  const int ldso = w * 16 * 32;

  for (int kk = 0; kk < K; kk += 32) {
    gl_lds16(pA + kk, As + ldso);
    gl_lds16(pW + kk, Ws + ldso);
    __syncthreads();

    bf16x8 af[2], bf[2];
#pragma unroll
    for (int i = 0; i < 2; i++) {
      int ar = wm * 32 + i * 16 + l16;
      af[i] = *(const bf16x8*)&As[ar * 32 + ((quad ^ ((ar >> 1) & 3)) * 8)];
      int br = wn * 32 + i * 16 + l16;
      bf[i] = *(const bf16x8*)&Ws[br * 32 + ((quad ^ ((br >> 1) & 3)) * 8)];
    }
#pragma unroll
    for (int mt = 0; mt < 2; mt++)
#pragma unroll
      for (int nt = 0; nt < 2; nt++)
        acc[mt][nt] = MFMA_BF16(af[mt], bf[nt], acc[mt][nt]);
    __syncthreads();
  }

#pragma unroll
  for (int mt = 0; mt < 2; mt++) {
#pragma unroll
    for (int nt = 0; nt < 2; nt++) {
      const int row = m0 + wm * 32 + mt * 16 + quad * 4;
      const int col = n0 + wn * 32 + nt * 16 + l16;
#pragma unroll
      for (int rg = 0; rg < 4; rg++) Cf[(size_t)(row + rg) * N + col] = acc[mt][nt][rg];
    }
  }
}

// ---------------- flash attention v6: transposed scores -------------------
__global__ __launch_bounds__(256) void flash_kernel(
    const bfloat* __restrict__ qh, const bfloat* __restrict__ ql,
    const bfloat* __restrict__ kh, const bfloat* __restrict__ kl,
    const bfloat* __restrict__ vt, bfloat* __restrict__ outp) {
  __shared__ __align__(16) bfloat Kh[64 * 64];
  __shared__ __align__(16) bfloat Kl[64 * 64];
  __shared__ __align__(16) bfloat Vt[64 * 64];
  __shared__ __align__(16) bfloat Pm[64 * 64];

  const int t = threadIdx.x;
  const int w = t >> 6, lane = t & 63;
  const int quad = lane >> 4, l16 = lane & 15;
  const int b = blockIdx.z, h = blockIdx.y;
  const int q0 = blockIdx.x * 64;
  const size_t base = (size_t)b * S * D + (size_t)h * DH;       // [b][s][n]
  const size_t vbase = (size_t)b * D * S + (size_t)h * DH * S;  // [b][n][s]

  const int ssr = lane >> 3;
  const int spc = lane & 7;

  bf16x8 ones;
#pragma unroll
  for (int j = 0; j < 8; j++) ones[j] = (bfloat)1.f;

  // ---- prologue: stage Q hi/lo through K buffers; B-frags to registers ----
#pragma unroll
  for (int g = 0; g < 2; g++) {
    int r = w * 16 + g * 8 + ssr;
    int c = spc ^ (r & 7);
    int lo = (w * 16 + g * 8) * 64;
    gl_lds16(qh + base + (size_t)(q0 + r) * D + c * 8, Kh + lo);
    gl_lds16(ql + base + (size_t)(q0 + r) * D + c * 8, Kl + lo);
  }
  __syncthreads();
  bf16x8 qhf[2], qlf[2];
  {
    int row = w * 16 + l16;
#pragma unroll
    for (int s2 = 0; s2 < 2; s2++) {
      qhf[s2] = *(const bf16x8*)&Kh[row * 64 + (((s2 * 4 + quad) ^ (l16 & 7)) * 8)];
      qlf[s2] = *(const bf16x8*)&Kl[row * 64 + (((s2 * 4 + quad) ^ (l16 & 7)) * 8)];
    }
  }
  __syncthreads();  // Q frag reads done before first K staging

  f32x4 Oa[4] = {};  // O^T: elem rg -> dim=mt*16+quad*4+rg, qrow=l16
  f32x4 La = {};     // all regs equal: sum_k P (per qrow=l16)
  float m_i = -3.0e38f;

  for (int k0 = 0; k0 < S; k0 += 64) {
#pragma unroll
    for (int g = 0; g < 2; g++) {
      int r = w * 16 + g * 8 + ssr;
      int c = spc ^ (r & 7);
      int lo = (w * 16 + g * 8) * 64;
      gl_lds16(kh + base + (size_t)(k0 + r) * D + c * 8, Kh + lo);
      gl_lds16(kl + base + (size_t)(k0 + r) * D + c * 8, Kl + lo);
      gl_lds16(vt + vbase + (size_t)r * S + k0 + c * 8, Vt + lo);
    }
    __syncthreads();

    // S^T = Kh*Qh + Kl*Qh + Kh*Ql (pre-scaled, log2 domain)
    f32x4 sf[4];
#pragma unroll
    for (int mt = 0; mt < 4; mt++) {
      f32x4 a = {};
      int krow = mt * 16 + l16;
#pragma unroll
      for (int s2 = 0; s2 < 2; s2++) {
        bf16x8 bh = *(const bf16x8*)&Kh[krow * 64 + (((s2 * 4 + quad) ^ (l16 & 7)) * 8)];
        bf16x8 bl = *(const bf16x8*)&Kl[krow * 64 + (((s2 * 4 + quad) ^ (l16 & 7)) * 8)];
        a = MFMA_BF16(bh, qhf[s2], a);
        a = MFMA_BF16(bl, qhf[s2], a);
        a = MFMA_BF16(bh, qlf[s2], a);
      }
      sf[mt] = a;
    }

    // online softmax: lane-scalar state (qrow = l16)
    float mm = sf[0][0];
#pragma unroll
    for (int mt = 0; mt < 4; mt++)
#pragma unroll
      for (int rg = 0; rg < 4; rg++) mm = fmaxf(mm, sf[mt][rg]);
    mm = fmaxf(mm, __shfl_xor(mm, 16, 64));
    mm = fmaxf(mm, __shfl_xor(mm, 32, 64));
    if (__ballot(mm > m_i)) {  // wave-uniform skip when no lane's max moved
      float mnew = fmaxf(m_i, mm);
      float alpha = exp2f(m_i - mnew);
      m_i = mnew;
#pragma unroll
      for (int mt = 0; mt < 4; mt++) Oa[mt] *= alpha;
      La *= alpha;
    }
#pragma unroll
    for (int mt = 0; mt < 4; mt++)
#pragma unroll
      for (int rg = 0; rg < 4; rg++) sf[mt][rg] = exp2f(sf[mt][rg] - m_i);

    // P write: 4 consecutive keys per lane -> b64, 16B-granule swizzle
#pragma unroll
    for (int mt = 0; mt < 4; mt++) {
      bf16x4 pk;
#pragma unroll
      for (int rg = 0; rg < 4; rg++) pk[rg] = (bfloat)sf[mt][rg];
      int g16 = (mt * 2 + (quad >> 1)) ^ (l16 & 7);
      *(bf16x4*)&Pm[(w * 16 + l16) * 64 + g16 * 8 + (quad & 1) * 4] = pk;
    }

    // O^T += V^T * P^T ; La += ones * P^T  (Pm rows wave-private)
#pragma unroll
    for (int s2 = 0; s2 < 2; s2++) {
      bf16x8 pb = *(const bf16x8*)&Pm[(w * 16 + l16) * 64 +
                                      (((s2 * 4 + quad) ^ (l16 & 7)) * 8)];
#pragma unroll
      for (int mt = 0; mt < 4; mt++) {
        int vrow = mt * 16 + l16;
        bf16x8 va = *(const bf16x8*)&Vt[vrow * 64 + (((s2 * 4 + quad) ^ (l16 & 7)) * 8)];
        Oa[mt] = MFMA_BF16(va, pb, Oa[mt]);
      }
      La = MFMA_BF16(ones, pb, La);
    }
    __syncthreads();  // frag reads done before next iteration's staging
  }

  // epilogue: lane owns qrow=l16; 4 consecutive dims per mt -> b64 stores
  float inv = 1.0f / La[0];
  const int qrow = q0 + w * 16 + l16;
#pragma unroll
  for (int mt = 0; mt < 4; mt++) {
    bf16x4 ov;
#pragma unroll
    for (int rg = 0; rg < 4; rg++) ov[rg] = (bfloat)(Oa[mt][rg] * inv);
    *(bf16x4*)&outp[base + (size_t)qrow * D + mt * 16 + quad * 4] = ov;
  }
}

extern "C" void kernel_launch(void* const* d_in, const int* in_sizes, int n_in,
                              void* d_out, int out_size, void* d_ws, size_t ws_size,
                              hipStream_t stream) {
  const float* q_in = (const float*)d_in[0];
  const float* k_in = (const float*)d_in[1];
  const float* v_in = (const float*)d_in[2];
  const float* wq = (const float*)d_in[3];
  const float* wk = (const float*)d_in[4];
  const float* wv = (const float*)d_in[5];
  const float* wo = (const float*)d_in[6];
  float* outp = (float*)d_out;
  char* ws = (char*)d_ws;

  constexpr size_t WBYTES = (size_t)WMAT_N * 2;
  constexpr size_t XBYTES = (size_t)M * D * 2;
  size_t off = 0;
  double* sums = (double*)(ws + off); off += 256;
  bfloat* wqt = (bfloat*)(ws + off); off += WBYTES;
  bfloat* wkt = (bfloat*)(ws + off); off += WBYTES;
  bfloat* wvt = (bfloat*)(ws + off); off += WBYTES;
  bfloat* wot = (bfloat*)(ws + off); off += WBYTES;
  bfloat* xqh = (bfloat*)(ws + off); off += XBYTES;
  bfloat* xql = (bfloat*)(ws + off); off += XBYTES;
  bfloat* xkh = (bfloat*)(ws + off); off += XBYTES;
  bfloat* xkl = (bfloat*)(ws + off); off += XBYTES;
  bfloat* xvh = (bfloat*)(ws + off); off += XBYTES;
  bfloat* qmh = (bfloat*)(ws + off); off += XBYTES;
  bfloat* qml = (bfloat*)(ws + off); off += XBYTES;
  bfloat* kmh = (bfloat*)(ws + off); off += XBYTES;
  bfloat* kml = (bfloat*)(ws + off); off += XBYTES;
  bfloat* vtr = (bfloat*)(ws + off); off += XBYTES;  // V^T [B][D][S]
  bfloat* attn = xqh;  // dead after q projection

  hipMemsetAsync(sums, 0, 4 * sizeof(double), stream);
  prep_kernel<<<dim3(256, 7), 256, 0, stream>>>(
      wq, wk, wv, wo, q_in, k_in, v_in, xqh, xql, xkh, xkl, xvh, sums);
  tern_kernel<<<dim3(128, 4), 256, 0, stream>>>(wq, wk, wv, wo, wqt, wkt, wvt, wot, sums);
  qkv_gemm<<<dim3(D / 128, M / 128, 3), 256, 0, stream>>>(
      xqh, xql, xkh, xkl, xvh, wqt, wkt, wvt, qmh, qml, kmh, kml, vtr);
  flash_kernel<<<dim3(S / 64, H, B), 256, 0, stream>>>(qmh, qml, kmh, kml, vtr, attn);
  gemm_wo<<<dim3(D / 64, M / 64), 256, 0, stream>>>(attn, wot, outp);
}